// Round 16
// baseline (305.465 us; speedup 1.0000x reference)
//
#include <hip/hip_runtime.h>
#include <hip/hip_bf16.h>
#include <cstdint>
#include <cstddef>

#define NA   2048
#define NB   2048
#define DD   512

typedef __attribute__((ext_vector_type(8))) short bf16x8;
typedef __attribute__((ext_vector_type(4))) float f32x4;
typedef unsigned short u16;
typedef unsigned int   u32;

__device__ __forceinline__ u16 f2b_hw(float f) {
    u32 w;
    asm("v_cvt_pk_bf16_f32 %0, %1, %2" : "=v"(w) : "v"(f), "v"(f));
    return (u16)w;
}
__device__ __forceinline__ float b2f(u16 h) {
    return __uint_as_float(((u32)h) << 16);
}
__device__ __forceinline__ u32 umin32(u32 a, u32 b) { return a < b ? a : b; }
__device__ __forceinline__ u32 umax32(u32 a, u32 b) { return a > b ? a : b; }
__device__ __forceinline__ u32 med3u(u32 a, u32 b, u32 c) {
    return umax32(umin32(a, b), umin32(umax32(a, b), c));   // -> v_med3_u32
}
__device__ __forceinline__ bf16x8 cvt8(f32x4 v0, f32x4 v1) {
    u32 w0, w1, w2, w3;
    asm("v_cvt_pk_bf16_f32 %0, %1, %2" : "=v"(w0) : "v"(v0[0]), "v"(v0[1]));
    asm("v_cvt_pk_bf16_f32 %0, %1, %2" : "=v"(w1) : "v"(v0[2]), "v"(v0[3]));
    asm("v_cvt_pk_bf16_f32 %0, %1, %2" : "=v"(w2) : "v"(v1[0]), "v"(v1[1]));
    asm("v_cvt_pk_bf16_f32 %0, %1, %2" : "=v"(w3) : "v"(v1[2]), "v"(v1[3]));
    union { u32 u[4]; bf16x8 v; } cv;
    cv.u[0] = w0; cv.u[1] = w1; cv.u[2] = w2; cv.u[3] = w3;
    return cv.v;
}

#define GLDS16(gsrc, ldst)                                                  \
    __builtin_amdgcn_global_load_lds(                                       \
        (const __attribute__((address_space(1))) void*)(gsrc),              \
        (__attribute__((address_space(3))) void*)(ldst), 16, 0, 0)

// ---------------------------------------------------------------------------
// Zero the task/flag counters (fresh every launch -> graph-replay safe).
// ---------------------------------------------------------------------------
__global__ void init_ctr(u32* __restrict__ c) {
    if (threadIdx.x < 8) c[threadIdx.x] = 0;
}

// ---------------------------------------------------------------------------
// Coalesced LDS-transpose: W2T[n][k]=W[512+k][n], WdT[n][k]=W[k][n]-W[512+k][n]
// ---------------------------------------------------------------------------
__global__ __launch_bounds__(256) void prep_w(const float* __restrict__ W,
                                              u16* __restrict__ W2T,
                                              u16* __restrict__ WdT) {
    __shared__ float s2[64][65];
    __shared__ float sd[64][65];
    int kb = blockIdx.x * 64, nb = blockIdx.y * 64;
    int tid = threadIdx.x;
    int c = tid & 63, r0 = tid >> 6;
    #pragma unroll
    for (int p = 0; p < 16; ++p) {
        int r = p * 4 + r0;
        float w1 = W[(size_t)(kb + r) * DD + nb + c];
        float w2 = W[(size_t)(512 + kb + r) * DD + nb + c];
        s2[r][c] = w2;
        sd[r][c] = w1 - w2;
    }
    __syncthreads();
    #pragma unroll
    for (int p = 0; p < 16; ++p) {
        int n = p * 4 + r0;
        W2T[(size_t)(nb + n) * DD + kb + c] = f2b_hw(s2[c][n]);
        WdT[(size_t)(nb + n) * DD + kb + c] = f2b_hw(sd[c][n]);
    }
}

// ---------------------------------------------------------------------------
// Exact integer top-4 NN (lax.top_k tie-break). key=(s<<11)|j. Pure VALU.
// ---------------------------------------------------------------------------
__global__ __launch_bounds__(512) void topk_kernel(const int* __restrict__ ca,
                                                   const int* __restrict__ cb,
                                                   int* __restrict__ idx_out,
                                                   float* __restrict__ w_out) {
    __shared__ u32 pcb[NB];
    __shared__ u32 part[3 * 128 * 4];
    int b = blockIdx.y;
    int tid = threadIdx.x;
    for (int p = tid; p < NB; p += 512) {
        const int* c = cb + ((size_t)b * NB + p) * 3;
        pcb[p] = (u32)c[0] | ((u32)c[1] << 8) | ((u32)c[2] << 16);
    }
    __syncthreads();

    int q = tid & 127, g = tid >> 7;
    int i = blockIdx.x * 128 + q;
    const int* ac = ca + ((size_t)b * NA + i) * 3;
    int ax = ac[0], ay = ac[1], az = ac[2];

    u32 k0 = ~0u, k1 = ~0u, k2 = ~0u, k3 = ~0u;
    int j0 = g * 512;
    #pragma unroll 8
    for (int jj = 0; jj < 512; ++jj) {
        int j = j0 + jj;
        u32 p = pcb[j];
        int dx = ax - (int)(p & 255u);
        int dy = ay - (int)((p >> 8) & 255u);
        int dz = az - (int)(p >> 16);
        u32 s = (u32)(__mul24(dx, dx) + __mul24(dy, dy) + __mul24(dz, dz));
        u32 key = (s << 11) | (u32)j;
        u32 nk0 = umin32(k0, key);
        u32 nk1 = med3u(key, k0, k1);
        u32 nk2 = med3u(key, k1, k2);
        u32 nk3 = med3u(key, k2, k3);
        k0 = nk0; k1 = nk1; k2 = nk2; k3 = nk3;
    }
    if (g) {
        u32* pp = &part[((g - 1) * 128 + q) * 4];
        pp[0] = k0; pp[1] = k1; pp[2] = k2; pp[3] = k3;
    }
    __syncthreads();
    if (g == 0) {
        #pragma unroll
        for (int L = 0; L < 3; ++L) {
            const u32* pp = &part[(L * 128 + q) * 4];
            #pragma unroll
            for (int t = 0; t < 4; ++t) {
                u32 key = pp[t];
                u32 nk0 = umin32(k0, key);
                u32 nk1 = med3u(key, k0, k1);
                u32 nk2 = med3u(key, k1, k2);
                u32 nk3 = med3u(key, k2, k3);
                k0 = nk0; k1 = nk1; k2 = nk2; k3 = nk3;
            }
        }
        size_t o = ((size_t)b * NA + i) * 4;
        u32 ks[4] = {k0, k1, k2, k3};
        #pragma unroll
        for (int t = 0; t < 4; ++t) {
            idx_out[o + t] = (int)(ks[t] & 2047u);
            float d = sqrtf((float)(ks[t] >> 11)) * (1.0f / 128.0f);
            w_out[o + t] = 0.5f - fminf(d, 0.5f);
        }
    }
}

// ---------------------------------------------------------------------------
// Task-queue fat kernel: 1024 blocks grab tasks in dependency order.
//   task <  512 : gemm_Q tile  (Qb = fb @ WdT^T), release-flag on completion
//   task >= 512 : gemm_P tile  (K-loop + out-left copy + Ps spill overlap
//                 gemm_Q; then acquire-wait for all 512 Q flags; then the
//                 depth-2 Q[idx]-gather epilogue writes out[:,512+n0..+256)).
// Deadlock-free: tasks grabbed in dependency order, so a waiter's deps were
// grabbed by earlier-running blocks (retired or making progress).
// GEMM core: BM=128 BN=256 BK=32, f32-A via GLDS16 (src XOR-swizzled),
// cvt_pk at frag read, counted vmcnt(8), 2x32KB buffers. [R8: ~25us/512 tiles]
// ---------------------------------------------------------------------------
__global__ __launch_bounds__(256, 1) void fused_gemms(
    const float* __restrict__ fa, const float* __restrict__ fb,
    const u16* __restrict__ W2T, const u16* __restrict__ WdT,
    u16* __restrict__ Qb, const int* __restrict__ idxb,
    const float* __restrict__ wb, const float* __restrict__ bias,
    float* __restrict__ out, u32* __restrict__ ctr) {

    __shared__ __align__(16) char smem[66560];
    __shared__ int s_task;

    const int tid = threadIdx.x;
    if (tid == 0)
        s_task = (int)__hip_atomic_fetch_add(&ctr[0], 1u, __ATOMIC_RELAXED,
                                             __HIP_MEMORY_SCOPE_AGENT);
    __syncthreads();
    const int task = s_task;

    const int lane = tid & 63;
    const int wave = tid >> 6;
    const int l15  = lane & 15;
    const int fq   = lane >> 4;
    const int wr   = (wave >> 1) << 6;
    const int wc   = (wave & 1) << 7;
    const int r4   = (lane >> 4) * 4;

#define GEMM_SETUP(Aptr, BTptr)                                              \
    int aflat[4]; const float* asp[4];                                       \
    _Pragma("unroll") for (int i = 0; i < 4; ++i) {                          \
        int flat = i * 256 + tid;                                            \
        int row = flat >> 3, pq = flat & 7;                                  \
        aflat[i] = flat;                                                     \
        asp[i] = (Aptr) + (size_t)(m0 + row) * DD + ((pq ^ (row & 7)) << 2); \
    }                                                                        \
    int bflat[4]; const u16* bsp[4];                                         \
    _Pragma("unroll") for (int i = 0; i < 4; ++i) {                          \
        int flat = i * 256 + tid;                                            \
        int row = flat >> 2, pq = flat & 3;                                  \
        bflat[i] = flat;                                                     \
        bsp[i] = (BTptr) + (size_t)(n0 + row) * DD                           \
                 + ((pq ^ ((row >> 1) & 3)) << 3);                           \
    }                                                                        \
    int aoff[4][2], boff[8];                                                 \
    _Pragma("unroll") for (int mf = 0; mf < 4; ++mf) {                       \
        int R = wr + mf * 16 + l15;                                          \
        aoff[mf][0] = R * 128 + (((2 * fq) ^ (R & 7)) << 4);                 \
        aoff[mf][1] = R * 128 + (((2 * fq + 1) ^ (R & 7)) << 4);             \
    }                                                                        \
    _Pragma("unroll") for (int nf = 0; nf < 8; ++nf) {                       \
        int R = wc + nf * 16 + l15;                                          \
        boff[nf] = 16384 + R * 64 + ((fq ^ ((R >> 1) & 3)) << 4);            \
    }

#define STAGE(kk, bufb)                                                      \
    { _Pragma("unroll") for (int i = 0; i < 4; ++i)                          \
          GLDS16(asp[i] + (kk), smem + (bufb) + aflat[i] * 16);              \
      _Pragma("unroll") for (int i = 0; i < 4; ++i)                          \
          GLDS16(bsp[i] + (kk), smem + (bufb) + 16384 + bflat[i] * 16); }

#define GEMM_LOOP(acc)                                                       \
    STAGE(0, 0);                                                             \
    _Pragma("unroll 1") for (int t = 0; t < 16; ++t) {                       \
        const int cur = (t & 1) * 32768;                                     \
        if (t < 15) {                                                        \
            STAGE((t + 1) * 32, 32768 - cur);                                \
            asm volatile("s_waitcnt vmcnt(8)" ::: "memory");                 \
        } else {                                                             \
            asm volatile("s_waitcnt vmcnt(0)" ::: "memory");                 \
        }                                                                    \
        __builtin_amdgcn_s_barrier();                                        \
        bf16x8 af[4], bfr[8];                                                \
        _Pragma("unroll") for (int mf = 0; mf < 4; ++mf) {                   \
            f32x4 lo = *(const f32x4*)(smem + cur + aoff[mf][0]);            \
            f32x4 hi = *(const f32x4*)(smem + cur + aoff[mf][1]);            \
            af[mf] = cvt8(lo, hi);                                           \
        }                                                                    \
        _Pragma("unroll") for (int nf = 0; nf < 8; ++nf)                     \
            bfr[nf] = *(const bf16x8*)(smem + cur + boff[nf]);               \
        _Pragma("unroll") for (int mf = 0; mf < 4; ++mf)                     \
            _Pragma("unroll") for (int nf = 0; nf < 8; ++nf)                 \
                acc[mf][nf] = __builtin_amdgcn_mfma_f32_16x16x32_bf16(       \
                    af[mf], bfr[nf], acc[mf][nf], 0, 0, 0);                  \
        __builtin_amdgcn_s_barrier();                                        \
    }

    if (task < 512) {
        // ================= gemm_Q tile =====================================
        const int m0 = (task >> 1) << 7;
        const int n0 = (task & 1) << 8;
        GEMM_SETUP(fb, WdT);
        f32x4 acc[4][8];
        #pragma unroll
        for (int mf = 0; mf < 4; ++mf)
            #pragma unroll
            for (int nf = 0; nf < 8; ++nf)
                acc[mf][nf] = (f32x4){0.f, 0.f, 0.f, 0.f};
        GEMM_LOOP(acc);

        #pragma unroll
        for (int mf = 0; mf < 4; ++mf)
            #pragma unroll
            for (int nf = 0; nf < 8; ++nf)
                #pragma unroll
                for (int j = 0; j < 4; ++j) {
                    int row = m0 + wr + mf * 16 + r4 + j;
                    int col = n0 + wc + nf * 16 + l15;
                    Qb[(size_t)row * DD + col] = f2b_hw(acc[mf][nf][j]);
                }
        __syncthreads();                     // drains vmcnt per-wave
        if (tid == 0) {
            __threadfence();                 // write-back L2 (agent scope)
            __hip_atomic_fetch_add(&ctr[1], 1u, __ATOMIC_RELEASE,
                                   __HIP_MEMORY_SCOPE_AGENT);
        }
        return;
    }

    // ================= gemm_P tile (fused epilogue) ========================
    const int idxp = task - 512;
    const int mb   = idxp >> 1;
    const int m0   = ((((mb & 7) << 5) | (mb >> 3)) << 7);  // XCD m-swizzle
    const int n0   = (idxp & 1) << 8;
    GEMM_SETUP(fa, W2T);
    f32x4 acc[4][8];
    #pragma unroll
    for (int mf = 0; mf < 4; ++mf)
        #pragma unroll
        for (int nf = 0; nf < 8; ++nf)
            acc[mf][nf] = (f32x4){0.f, 0.f, 0.f, 0.f};
    GEMM_LOOP(acc);

    // ---- out-left copy: fa rows m0..+128, cols [n0..n0+256) (L3-hot) ------
    {
        const float* src = fa + (size_t)m0 * DD + n0;
        float*       dst = out + (size_t)m0 * 1024 + n0;
        #pragma unroll 4
        for (int it = 0; it < 32; ++it) {
            int flat = it * 256 + tid;
            int row = flat >> 6, qd = flat & 63;
            f32x4 v = *(const f32x4*)(src + (size_t)row * DD + qd * 4);
            *(f32x4*)(dst + (size_t)row * 1024 + qd * 4) = v;
        }
    }

    // ---- P' = acc + bias -> Ps (bf16) -------------------------------------
    const int g16 = tid >> 4, l16 = tid & 15;
    const int r0g = g16 * 8;
    const u16* qs = Qb + ((size_t)(m0 >> 11) << 20);   // batch * 2048 * 512

    int4 iv[8];
    #pragma unroll
    for (int k = 0; k < 8; ++k)
        iv[k] = *(const int4*)(idxb + (size_t)(m0 + r0g + k) * 4);

    float bi[8];
    #pragma unroll
    for (int nf = 0; nf < 8; ++nf)
        bi[nf] = bias[n0 + wc + nf * 16 + l15];

    u16* Ps = (u16*)smem;                    // [128][260] bf16, 66560 B
    #pragma unroll
    for (int mf = 0; mf < 4; ++mf)
        #pragma unroll
        for (int nf = 0; nf < 8; ++nf)
            #pragma unroll
            for (int j = 0; j < 4; ++j)
                Ps[(wr + mf * 16 + r4 + j) * 260 + wc + nf * 16 + l15] =
                    f2b_hw(acc[mf][nf][j] + bi[nf]);

    // ---- wait for ALL gemm_Q tiles (acquire) ------------------------------
    if (tid == 0) {
        while (__hip_atomic_load(&ctr[1], __ATOMIC_RELAXED,
                                 __HIP_MEMORY_SCOPE_AGENT) < 512u)
            __builtin_amdgcn_s_sleep(2);
        (void)__hip_atomic_load(&ctr[1], __ATOMIC_ACQUIRE,
                                __HIP_MEMORY_SCOPE_AGENT);
    }
    __syncthreads();                         // Ps visible + all waves gated
    __threadfence();                         // per-wave cache invalidate

    // ---- depth-2 gather pipeline (two static reg banks) -------------------
    bf16x8 qA0[8], qA1[8];

#define QLOAD(BANK, k)                                                       \
    { const size_t rx = (size_t)iv[k].x * DD, ry = (size_t)iv[k].y * DD,     \
                   rz = (size_t)iv[k].z * DD, rw = (size_t)iv[k].w * DD;     \
      _Pragma("unroll") for (int cc = 0; cc < 2; ++cc) {                     \
          const int col = n0 + cc * 128 + l16 * 8;                           \
          BANK[cc*4+0] = *(const bf16x8*)(qs + rx + col);                    \
          BANK[cc*4+1] = *(const bf16x8*)(qs + ry + col);                    \
          BANK[cc*4+2] = *(const bf16x8*)(qs + rz + col);                    \
          BANK[cc*4+3] = *(const bf16x8*)(qs + rw + col);                    \
      } }

#define QCONSUME(BANK, k)                                                    \
    { f32x4 wv = *(const f32x4*)(wb + (size_t)(m0 + r0g + (k)) * 4);         \
      _Pragma("unroll") for (int cc = 0; cc < 2; ++cc) {                     \
          const int col = cc * 128 + l16 * 8;                                \
          bf16x8 p8 = *(const bf16x8*)(Ps + (r0g + (k)) * 260 + col);        \
          float o[8];                                                        \
          _Pragma("unroll") for (int j = 0; j < 8; ++j) {                    \
              float p = b2f((u16)p8[j]);                                     \
              float s;                                                       \
              s  = fmaxf(p + b2f((u16)BANK[cc*4+0][j]), 0.f) * wv[0];        \
              s += fmaxf(p + b2f((u16)BANK[cc*4+1][j]), 0.f) * wv[1];        \
              s += fmaxf(p + b2f((u16)BANK[cc*4+2][j]), 0.f) * wv[2];        \
              s += fmaxf(p + b2f((u16)BANK[cc*4+3][j]), 0.f) * wv[3];        \
              o[j] = s;                                                      \
          }                                                                  \
          float* op = out + (size_t)(m0 + r0g + (k)) * 1024 + 512 + n0 + col;\
          *(f32x4*)op       = (f32x4){o[0], o[1], o[2], o[3]};               \
          *(f32x4*)(op + 4) = (f32x4){o[4], o[5], o[6], o[7]};               \
      } }

    QLOAD(qA0, 0);
    QLOAD(qA1, 1);
    QCONSUME(qA0, 0); QLOAD(qA0, 2);
    QCONSUME(qA1, 1); QLOAD(qA1, 3);
    QCONSUME(qA0, 2); QLOAD(qA0, 4);
    QCONSUME(qA1, 3); QLOAD(qA1, 5);
    QCONSUME(qA0, 4); QLOAD(qA0, 6);
    QCONSUME(qA1, 5); QLOAD(qA1, 7);
    QCONSUME(qA0, 6);
    QCONSUME(qA1, 7);
}

extern "C" void kernel_launch(void* const* d_in, const int* in_sizes, int n_in,
                              void* d_out, int out_size, void* d_ws, size_t ws_size,
                              hipStream_t stream) {
    const float* fa   = (const float*)d_in[0];
    const float* fb   = (const float*)d_in[1];
    const float* W    = (const float*)d_in[2];
    const float* bias = (const float*)d_in[3];
    const int*   ca   = (const int*)d_in[4];
    const int*   cb   = (const int*)d_in[5];
    float* out = (float*)d_out;

    char* ws = (char*)d_ws;
    u16*   Qb   = (u16*)(ws);                       // 32 MB bf16 Q
    u16*   W2T  = (u16*)(ws + 33554432);            // 512 KB
    u16*   WdT  = (u16*)(ws + 34078720);            // 512 KB
    int*   idxb = (int*)(ws + 34603008);            // 512 KB
    float* wb   = (float*)(ws + 35127296);          // 512 KB
    u32*   ctr  = (u32*)(ws + 35651584);            // 32 B task/flag counters

    init_ctr<<<1, 64, 0, stream>>>(ctr);

    dim3 pg(8, 8);
    prep_w<<<pg, 256, 0, stream>>>(W, W2T, WdT);

    dim3 tg(16, 16);
    topk_kernel<<<tg, 512, 0, stream>>>(ca, cb, idxb, wb);

    fused_gemms<<<1024, 256, 0, stream>>>(fa, fb, W2T, WdT, Qb, idxb, wb,
                                          bias, out, ctr);
}

// Round 17
// 136.414 us; speedup vs baseline: 2.2393x; 2.2393x over previous
//
#include <hip/hip_runtime.h>
#include <hip/hip_bf16.h>
#include <cstdint>
#include <cstddef>

#define NA   2048
#define NB   2048
#define DD   512

typedef __attribute__((ext_vector_type(8))) short bf16x8;
typedef __attribute__((ext_vector_type(4))) float f32x4;
typedef unsigned short u16;
typedef unsigned int   u32;

__device__ __forceinline__ u16 f2b_hw(float f) {
    u32 w;
    asm("v_cvt_pk_bf16_f32 %0, %1, %2" : "=v"(w) : "v"(f), "v"(f));
    return (u16)w;
}
__device__ __forceinline__ float b2f(u16 h) {
    return __uint_as_float(((u32)h) << 16);
}
__device__ __forceinline__ u32 umin32(u32 a, u32 b) { return a < b ? a : b; }
__device__ __forceinline__ u32 umax32(u32 a, u32 b) { return a > b ? a : b; }
__device__ __forceinline__ u32 med3u(u32 a, u32 b, u32 c) {
    return umax32(umin32(a, b), umin32(umax32(a, b), c));   // -> v_med3_u32
}
__device__ __forceinline__ bf16x8 cvt8(f32x4 v0, f32x4 v1) {
    u32 w0, w1, w2, w3;
    asm("v_cvt_pk_bf16_f32 %0, %1, %2" : "=v"(w0) : "v"(v0[0]), "v"(v0[1]));
    asm("v_cvt_pk_bf16_f32 %0, %1, %2" : "=v"(w1) : "v"(v0[2]), "v"(v0[3]));
    asm("v_cvt_pk_bf16_f32 %0, %1, %2" : "=v"(w2) : "v"(v1[0]), "v"(v1[1]));
    asm("v_cvt_pk_bf16_f32 %0, %1, %2" : "=v"(w3) : "v"(v1[2]), "v"(v1[3]));
    union { u32 u[4]; bf16x8 v; } cv;
    cv.u[0] = w0; cv.u[1] = w1; cv.u[2] = w2; cv.u[3] = w3;
    return cv.v;
}

#define GLDS16(gsrc, ldst)                                                  \
    __builtin_amdgcn_global_load_lds(                                       \
        (const __attribute__((address_space(1))) void*)(gsrc),              \
        (__attribute__((address_space(3))) void*)(ldst), 16, 0, 0)

// ---------------------------------------------------------------------------
// Fused topk + copy + prep_w. 1D grid of 320 blocks x 512 threads:
//   bid < 256 : exact integer top-4 NN for 128 queries (lax.top_k tie-break)
//               + fa -> out[:,0:512] copy for 128 rows (R3-proven placement)
//   bid >= 256: prep_w tile — W2T[n][k]=W[512+k][n], WdT=W[k][n]-W[512+k][n]
// ---------------------------------------------------------------------------
__global__ __launch_bounds__(512) void topk_prep(
    const int* __restrict__ ca, const int* __restrict__ cb,
    int* __restrict__ idx_out, float* __restrict__ w_out,
    const float* __restrict__ fa, float* __restrict__ out,
    const float* __restrict__ W, u16* __restrict__ W2T,
    u16* __restrict__ WdT) {

    __shared__ __align__(16) char smem[33280];
    const int bid = blockIdx.x;
    const int tid = threadIdx.x;

    if (bid >= 256) {
        // ================= prep_w tile (64 x 64), 512 threads ==============
        float (*s2)[65] = (float(*)[65])smem;            // 16640 B
        float (*sd)[65] = (float(*)[65])(smem + 16640);  // 16640 B
        const int pid = bid - 256;
        const int kb = (pid >> 3) * 64, nb = (pid & 7) * 64;
        const int c = tid & 63, r0 = tid >> 6;           // r0: 0..7
        #pragma unroll
        for (int p = 0; p < 8; ++p) {
            int r = p * 8 + r0;
            float w1 = W[(size_t)(kb + r) * DD + nb + c];
            float w2 = W[(size_t)(512 + kb + r) * DD + nb + c];
            s2[r][c] = w2;
            sd[r][c] = w1 - w2;
        }
        __syncthreads();
        #pragma unroll
        for (int p = 0; p < 8; ++p) {
            int n = p * 8 + r0;
            W2T[(size_t)(nb + n) * DD + kb + c] = f2b_hw(s2[c][n]);
            WdT[(size_t)(nb + n) * DD + kb + c] = f2b_hw(sd[c][n]);
        }
        return;
    }

    // ================= topk for 128 queries ================================
    u32* pcb  = (u32*)smem;              // 2048 packed coords, 8 KB
    u32* part = (u32*)(smem + 8192);     // groups 1..3 partials, 6 KB
    const int b  = bid >> 4;
    const int i0 = (bid & 15) << 7;
    for (int p = tid; p < NB; p += 512) {
        const int* c = cb + ((size_t)b * NB + p) * 3;
        pcb[p] = (u32)c[0] | ((u32)c[1] << 8) | ((u32)c[2] << 16);
    }
    __syncthreads();

    int q = tid & 127, g = tid >> 7;
    int i = i0 + q;
    const int* ac = ca + ((size_t)b * NA + i) * 3;
    int ax = ac[0], ay = ac[1], az = ac[2];

    u32 k0 = ~0u, k1 = ~0u, k2 = ~0u, k3 = ~0u;
    int j0 = g * 512;
    #pragma unroll 8
    for (int jj = 0; jj < 512; ++jj) {
        int j = j0 + jj;
        u32 p = pcb[j];
        int dx = ax - (int)(p & 255u);
        int dy = ay - (int)((p >> 8) & 255u);
        int dz = az - (int)(p >> 16);
        u32 s = (u32)(__mul24(dx, dx) + __mul24(dy, dy) + __mul24(dz, dz));
        u32 key = (s << 11) | (u32)j;
        u32 nk0 = umin32(k0, key);
        u32 nk1 = med3u(key, k0, k1);
        u32 nk2 = med3u(key, k1, k2);
        u32 nk3 = med3u(key, k2, k3);
        k0 = nk0; k1 = nk1; k2 = nk2; k3 = nk3;
    }
    if (g) {
        u32* pp = &part[((g - 1) * 128 + q) * 4];
        pp[0] = k0; pp[1] = k1; pp[2] = k2; pp[3] = k3;
    }
    __syncthreads();
    if (g == 0) {
        #pragma unroll
        for (int L = 0; L < 3; ++L) {
            const u32* pp = &part[(L * 128 + q) * 4];
            #pragma unroll
            for (int t = 0; t < 4; ++t) {
                u32 key = pp[t];
                u32 nk0 = umin32(k0, key);
                u32 nk1 = med3u(key, k0, k1);
                u32 nk2 = med3u(key, k1, k2);
                u32 nk3 = med3u(key, k2, k3);
                k0 = nk0; k1 = nk1; k2 = nk2; k3 = nk3;
            }
        }
        size_t o = ((size_t)b * NA + i) * 4;
        u32 ks[4] = {k0, k1, k2, k3};
        #pragma unroll
        for (int t = 0; t < 4; ++t) {
            idx_out[o + t] = (int)(ks[t] & 2047u);
            float d = sqrtf((float)(ks[t] >> 11)) * (1.0f / 128.0f);
            w_out[o + t] = 0.5f - fminf(d, 0.5f);
        }
    }

    // ---- fa -> out[:,0:512] copy: this block handles 128 rows -------------
    const float* src = fa + (size_t)bid * 128 * DD;
    float* dst = out + (size_t)bid * 128 * 1024;
    #pragma unroll 4
    for (int it = 0; it < 32; ++it) {
        int flat = it * 512 + tid;
        int row = flat >> 7;
        int c4  = flat & 127;
        f32x4 v = *(const f32x4*)(src + (size_t)row * DD + c4 * 4);
        *(f32x4*)(dst + (size_t)row * 1024 + c4 * 4) = v;
    }
}

// ---------------------------------------------------------------------------
// C = A(f32) @ BT^T(bf16). BM=128, BN=256, BK=32, 4 waves (64m x 128n).
// A staged f32 via GLDS16 (src XOR-swizzled), cvt_pk->bf16 at fragment read.
// T4 counted-vmcnt pipeline: STAGE(t+1); vmcnt(8); barrier; compute; barrier.
// FUSED (P path): XCD m-swizzle, fused bias+relu+Q[idx]-gather epilogue with
// depth-2 gather pipeline (hoisted idx, two static reg banks). No copy here.
// ---------------------------------------------------------------------------
template<bool FUSED>
__global__ __launch_bounds__(256, 1) void gemm_kernel(
    const float* __restrict__ A, const u16* __restrict__ BT,
    u16* __restrict__ C, const int* __restrict__ idxb,
    const float* __restrict__ wb, const float* __restrict__ bias,
    const u16* __restrict__ Qb, float* __restrict__ out) {

    __shared__ __align__(16) char smem[FUSED ? 66560 : 65536];

    const int tid  = threadIdx.x;
    const int lane = tid & 63;
    const int wave = tid >> 6;
    const int mb   = blockIdx.x;
    const int m0   = FUSED ? ((((mb & 7) << 5) | (mb >> 3)) << 7) : (mb << 7);
    const int n0   = blockIdx.y << 8;
    const int l15  = lane & 15;
    const int fq   = lane >> 4;              // 0..3
    const int wr   = (wave >> 1) << 6;
    const int wc   = (wave & 1) << 7;

    // ---- staging descriptors: LDS dest linear, SOURCE pre-swizzled --------
    int aflat[4]; const float* asp[4];
    #pragma unroll
    for (int i = 0; i < 4; ++i) {
        int flat = i * 256 + tid;            // A: 128 rows x 8 f32 16B-quads
        int row = flat >> 3, pq = flat & 7;
        aflat[i] = flat;
        asp[i] = A + (size_t)(m0 + row) * DD + ((pq ^ (row & 7)) << 2);
    }
    int bflat[4]; const u16* bsp[4];
    #pragma unroll
    for (int i = 0; i < 4; ++i) {
        int flat = i * 256 + tid;            // B: 256 rows x 4 bf16 16B-quads
        int row = flat >> 2, pq = flat & 3;
        bflat[i] = flat;
        bsp[i] = BT + (size_t)(n0 + row) * DD + ((pq ^ ((row >> 1) & 3)) << 3);
    }

    // ---- fragment LDS byte offsets (same involution on read) --------------
    int aoff[4][2], boff[8];
    #pragma unroll
    for (int mf = 0; mf < 4; ++mf) {
        int R = wr + mf * 16 + l15;
        aoff[mf][0] = R * 128 + (((2 * fq) ^ (R & 7)) << 4);
        aoff[mf][1] = R * 128 + (((2 * fq + 1) ^ (R & 7)) << 4);
    }
    #pragma unroll
    for (int nf = 0; nf < 8; ++nf) {
        int R = wc + nf * 16 + l15;
        boff[nf] = 16384 + R * 64 + ((fq ^ ((R >> 1) & 3)) << 4);
    }

    f32x4 acc[4][8];
    #pragma unroll
    for (int mf = 0; mf < 4; ++mf)
        #pragma unroll
        for (int nf = 0; nf < 8; ++nf)
            acc[mf][nf] = (f32x4){0.f, 0.f, 0.f, 0.f};

#define STAGE(kk, bufb)                                                      \
    { _Pragma("unroll") for (int i = 0; i < 4; ++i)                          \
          GLDS16(asp[i] + (kk), smem + (bufb) + aflat[i] * 16);              \
      _Pragma("unroll") for (int i = 0; i < 4; ++i)                          \
          GLDS16(bsp[i] + (kk), smem + (bufb) + 16384 + bflat[i] * 16); }

    STAGE(0, 0);

    #pragma unroll 1
    for (int t = 0; t < 16; ++t) {
        const int cur = (t & 1) * 32768;
        if (t < 15) {
            STAGE((t + 1) * 32, 32768 - cur);
            asm volatile("s_waitcnt vmcnt(8)" ::: "memory");   // stage t done
        } else {
            asm volatile("s_waitcnt vmcnt(0)" ::: "memory");
        }
        __builtin_amdgcn_s_barrier();        // all waves' stage t visible

        bf16x8 af[4], bfr[8];
        #pragma unroll
        for (int mf = 0; mf < 4; ++mf) {
            f32x4 lo = *(const f32x4*)(smem + cur + aoff[mf][0]);
            f32x4 hi = *(const f32x4*)(smem + cur + aoff[mf][1]);
            af[mf] = cvt8(lo, hi);
        }
        #pragma unroll
        for (int nf = 0; nf < 8; ++nf)
            bfr[nf] = *(const bf16x8*)(smem + cur + boff[nf]);
        #pragma unroll
        for (int mf = 0; mf < 4; ++mf)
            #pragma unroll
            for (int nf = 0; nf < 8; ++nf)
                acc[mf][nf] = __builtin_amdgcn_mfma_f32_16x16x32_bf16(
                    af[mf], bfr[nf], acc[mf][nf], 0, 0, 0);

        __builtin_amdgcn_s_barrier();        // buf may be overwritten next t
    }

    const int r4 = (lane >> 4) * 4;

    if (!FUSED) {
        #pragma unroll
        for (int mf = 0; mf < 4; ++mf)
            #pragma unroll
            for (int nf = 0; nf < 8; ++nf)
                #pragma unroll
                for (int j = 0; j < 4; ++j) {
                    int row = m0 + wr + mf * 16 + r4 + j;
                    int col = n0 + wc + nf * 16 + l15;
                    C[(size_t)row * DD + col] = f2b_hw(acc[mf][nf][j]);
                }
        return;
    }

    // ---- fused epilogue: P' = acc + bias -> Ps (bf16), gather Q[idx] ------
    const int g16 = tid >> 4, l16 = tid & 15;
    const int r0g = g16 * 8;
    const u16* qs = Qb + ((size_t)(m0 >> 11) << 20);   // batch * 2048 * 512

    // hoist idx rows (latency hides under Ps write + barrier)
    int4 iv[8];
    #pragma unroll
    for (int k = 0; k < 8; ++k)
        iv[k] = *(const int4*)(idxb + (size_t)(m0 + r0g + k) * 4);

    float bi[8];
    #pragma unroll
    for (int nf = 0; nf < 8; ++nf)
        bi[nf] = bias[n0 + wc + nf * 16 + l15];

    u16* Ps = (u16*)smem;                    // [128][260] bf16, 66560 B
    #pragma unroll
    for (int mf = 0; mf < 4; ++mf)
        #pragma unroll
        for (int nf = 0; nf < 8; ++nf)
            #pragma unroll
            for (int j = 0; j < 4; ++j)
                Ps[(wr + mf * 16 + r4 + j) * 260 + wc + nf * 16 + l15] =
                    f2b_hw(acc[mf][nf][j] + bi[nf]);

    // depth-2 gather pipeline: two static register banks (rule #20)
    bf16x8 qA0[8], qA1[8];

#define QLOAD(BANK, k)                                                       \
    { const size_t rx = (size_t)iv[k].x * DD, ry = (size_t)iv[k].y * DD,     \
                   rz = (size_t)iv[k].z * DD, rw = (size_t)iv[k].w * DD;     \
      _Pragma("unroll") for (int cc = 0; cc < 2; ++cc) {                     \
          const int col = n0 + cc * 128 + l16 * 8;                           \
          BANK[cc*4+0] = *(const bf16x8*)(qs + rx + col);                    \
          BANK[cc*4+1] = *(const bf16x8*)(qs + ry + col);                    \
          BANK[cc*4+2] = *(const bf16x8*)(qs + rz + col);                    \
          BANK[cc*4+3] = *(const bf16x8*)(qs + rw + col);                    \
      } }

#define QCONSUME(BANK, k)                                                    \
    { f32x4 wv = *(const f32x4*)(wb + (size_t)(m0 + r0g + (k)) * 4);         \
      _Pragma("unroll") for (int cc = 0; cc < 2; ++cc) {                     \
          const int col = cc * 128 + l16 * 8;                                \
          bf16x8 p8 = *(const bf16x8*)(Ps + (r0g + (k)) * 260 + col);        \
          float o[8];                                                        \
          _Pragma("unroll") for (int j = 0; j < 8; ++j) {                    \
              float p = b2f((u16)p8[j]);                                     \
              float s;                                                       \
              s  = fmaxf(p + b2f((u16)BANK[cc*4+0][j]), 0.f) * wv[0];        \
              s += fmaxf(p + b2f((u16)BANK[cc*4+1][j]), 0.f) * wv[1];        \
              s += fmaxf(p + b2f((u16)BANK[cc*4+2][j]), 0.f) * wv[2];        \
              s += fmaxf(p + b2f((u16)BANK[cc*4+3][j]), 0.f) * wv[3];        \
              o[j] = s;                                                      \
          }                                                                  \
          float* op = out + (size_t)(m0 + r0g + (k)) * 1024 + 512 + n0 + col;\
          *(f32x4*)op       = (f32x4){o[0], o[1], o[2], o[3]};               \
          *(f32x4*)(op + 4) = (f32x4){o[4], o[5], o[6], o[7]};               \
      } }

    // issue first two gather batches before the barrier (in flight across it)
    QLOAD(qA0, 0);
    QLOAD(qA1, 1);
    __syncthreads();

    QCONSUME(qA0, 0); QLOAD(qA0, 2);
    QCONSUME(qA1, 1); QLOAD(qA1, 3);
    QCONSUME(qA0, 2); QLOAD(qA0, 4);
    QCONSUME(qA1, 3); QLOAD(qA1, 5);
    QCONSUME(qA0, 4); QLOAD(qA0, 6);
    QCONSUME(qA1, 5); QLOAD(qA1, 7);
    QCONSUME(qA0, 6);
    QCONSUME(qA1, 7);
}

extern "C" void kernel_launch(void* const* d_in, const int* in_sizes, int n_in,
                              void* d_out, int out_size, void* d_ws, size_t ws_size,
                              hipStream_t stream) {
    const float* fa   = (const float*)d_in[0];
    const float* fb   = (const float*)d_in[1];
    const float* W    = (const float*)d_in[2];
    const float* bias = (const float*)d_in[3];
    const int*   ca   = (const int*)d_in[4];
    const int*   cb   = (const int*)d_in[5];
    float* out = (float*)d_out;

    char* ws = (char*)d_ws;
    u16*   Qb   = (u16*)(ws);                       // 32 MB bf16 Q
    u16*   W2T  = (u16*)(ws + 33554432);            // 512 KB
    u16*   WdT  = (u16*)(ws + 34078720);            // 512 KB
    int*   idxb = (int*)(ws + 34603008);            // 512 KB
    float* wb   = (float*)(ws + 35127296);          // 512 KB

    topk_prep<<<320, 512, 0, stream>>>(ca, cb, idxb, wb, fa, out,
                                       W, W2T, WdT);

    dim3 gg(256, 2);
    gemm_kernel<false><<<gg, 256, 0, stream>>>(fb, WdT, Qb, nullptr, nullptr,
                                               nullptr, nullptr, nullptr);
    gemm_kernel<true><<<gg, 256, 0, stream>>>(fa, W2T, nullptr, idxb, wb,
                                              bias, Qb, out);
}

// Round 18
// 125.793 us; speedup vs baseline: 2.4283x; 1.0844x over previous
//
#include <hip/hip_runtime.h>
#include <hip/hip_bf16.h>
#include <cstdint>
#include <cstddef>

#define NA   2048
#define NB   2048
#define DD   512

typedef __attribute__((ext_vector_type(8))) short bf16x8;
typedef __attribute__((ext_vector_type(4))) float f32x4;
typedef unsigned short u16;
typedef unsigned int   u32;

__device__ __forceinline__ u16 f2b_hw(float f) {
    u32 w;
    asm("v_cvt_pk_bf16_f32 %0, %1, %2" : "=v"(w) : "v"(f), "v"(f));
    return (u16)w;
}
__device__ __forceinline__ float b2f(u16 h) {
    return __uint_as_float(((u32)h) << 16);
}
__device__ __forceinline__ u32 umin32(u32 a, u32 b) { return a < b ? a : b; }
__device__ __forceinline__ u32 umax32(u32 a, u32 b) { return a > b ? a : b; }
__device__ __forceinline__ u32 med3u(u32 a, u32 b, u32 c) {
    return umax32(umin32(a, b), umin32(umax32(a, b), c));   // -> v_med3_u32
}
__device__ __forceinline__ bf16x8 cvt8(f32x4 v0, f32x4 v1) {
    u32 w0, w1, w2, w3;
    asm("v_cvt_pk_bf16_f32 %0, %1, %2" : "=v"(w0) : "v"(v0[0]), "v"(v0[1]));
    asm("v_cvt_pk_bf16_f32 %0, %1, %2" : "=v"(w1) : "v"(v0[2]), "v"(v0[3]));
    asm("v_cvt_pk_bf16_f32 %0, %1, %2" : "=v"(w2) : "v"(v1[0]), "v"(v1[1]));
    asm("v_cvt_pk_bf16_f32 %0, %1, %2" : "=v"(w3) : "v"(v1[2]), "v"(v1[3]));
    union { u32 u[4]; bf16x8 v; } cv;
    cv.u[0] = w0; cv.u[1] = w1; cv.u[2] = w2; cv.u[3] = w3;
    return cv.v;
}

#define GLDS16(gsrc, ldst)                                                  \
    __builtin_amdgcn_global_load_lds(                                       \
        (const __attribute__((address_space(1))) void*)(gsrc),              \
        (__attribute__((address_space(3))) void*)(ldst), 16, 0, 0)

// ---------------------------------------------------------------------------
// Fused topk + copy + prep_w. 1D grid of 320 blocks x 512 threads:
//   bid < 256 : exact integer top-4 NN for 128 queries (lax.top_k tie-break)
//               with the fa -> out[:,0:512] copy SOFTWARE-PIPELINED under the
//               VALU distance loop (4 chunks: 8 loads / 128 iters / 8 stores)
//   bid >= 256: prep_w tile — W2T[n][k]=W[512+k][n], WdT=W[k][n]-W[512+k][n]
// ---------------------------------------------------------------------------
__global__ __launch_bounds__(512) void topk_prep(
    const int* __restrict__ ca, const int* __restrict__ cb,
    int* __restrict__ idx_out, float* __restrict__ w_out,
    const float* __restrict__ fa, float* __restrict__ out,
    const float* __restrict__ W, u16* __restrict__ W2T,
    u16* __restrict__ WdT) {

    __shared__ __align__(16) char smem[33280];
    const int bid = blockIdx.x;
    const int tid = threadIdx.x;

    if (bid >= 256) {
        // ================= prep_w tile (64 x 64), 512 threads ==============
        float (*s2)[65] = (float(*)[65])smem;            // 16640 B
        float (*sd)[65] = (float(*)[65])(smem + 16640);  // 16640 B
        const int pid = bid - 256;
        const int kb = (pid >> 3) * 64, nb = (pid & 7) * 64;
        const int c = tid & 63, r0 = tid >> 6;           // r0: 0..7
        #pragma unroll
        for (int p = 0; p < 8; ++p) {
            int r = p * 8 + r0;
            float w1 = W[(size_t)(kb + r) * DD + nb + c];
            float w2 = W[(size_t)(512 + kb + r) * DD + nb + c];
            s2[r][c] = w2;
            sd[r][c] = w1 - w2;
        }
        __syncthreads();
        #pragma unroll
        for (int p = 0; p < 8; ++p) {
            int n = p * 8 + r0;
            W2T[(size_t)(nb + n) * DD + kb + c] = f2b_hw(s2[c][n]);
            WdT[(size_t)(nb + n) * DD + kb + c] = f2b_hw(sd[c][n]);
        }
        return;
    }

    // ================= topk (pipelined with fa -> out copy) ================
    u32* pcb  = (u32*)smem;              // 2048 packed coords, 8 KB
    u32* part = (u32*)(smem + 8192);     // groups 1..3 partials, 6 KB
    const int b  = bid >> 4;
    const int i0 = (bid & 15) << 7;
    for (int p = tid; p < NB; p += 512) {
        const int* c = cb + ((size_t)b * NB + p) * 3;
        pcb[p] = (u32)c[0] | ((u32)c[1] << 8) | ((u32)c[2] << 16);
    }
    __syncthreads();

    int q = tid & 127, g = tid >> 7;
    int i = i0 + q;
    const int* ac = ca + ((size_t)b * NA + i) * 3;
    int ax = ac[0], ay = ac[1], az = ac[2];

    const float* src = fa + (size_t)bid * 128 * DD;
    float*       dst = out + (size_t)bid * 128 * 1024;

    u32 k0 = ~0u, k1 = ~0u, k2 = ~0u, k3 = ~0u;
    int j0 = g * 512;

    #pragma unroll 1
    for (int c = 0; c < 4; ++c) {
        // issue this chunk's copy loads (latency hides under distance VALU)
        f32x4 tr[8];
        #pragma unroll
        for (int k = 0; k < 8; ++k) {
            int f = c * 4096 + k * 512 + tid;
            tr[k] = *(const f32x4*)(src + (size_t)(f >> 7) * DD + (f & 127) * 4);
        }
        // 128 distance iterations
        int jbase = j0 + c * 128;
        #pragma unroll 8
        for (int jj = 0; jj < 128; ++jj) {
            int j = jbase + jj;
            u32 p = pcb[j];
            int dx = ax - (int)(p & 255u);
            int dy = ay - (int)((p >> 8) & 255u);
            int dz = az - (int)(p >> 16);
            u32 s = (u32)(__mul24(dx, dx) + __mul24(dy, dy) + __mul24(dz, dz));
            u32 key = (s << 11) | (u32)j;
            u32 nk0 = umin32(k0, key);
            u32 nk1 = med3u(key, k0, k1);
            u32 nk2 = med3u(key, k1, k2);
            u32 nk3 = med3u(key, k2, k3);
            k0 = nk0; k1 = nk1; k2 = nk2; k3 = nk3;
        }
        // drain this chunk's copy stores
        #pragma unroll
        for (int k = 0; k < 8; ++k) {
            int f = c * 4096 + k * 512 + tid;
            *(f32x4*)(dst + (size_t)(f >> 7) * 1024 + (f & 127) * 4) = tr[k];
        }
    }

    if (g) {
        u32* pp = &part[((g - 1) * 128 + q) * 4];
        pp[0] = k0; pp[1] = k1; pp[2] = k2; pp[3] = k3;
    }
    __syncthreads();
    if (g == 0) {
        #pragma unroll
        for (int L = 0; L < 3; ++L) {
            const u32* pp = &part[(L * 128 + q) * 4];
            #pragma unroll
            for (int t = 0; t < 4; ++t) {
                u32 key = pp[t];
                u32 nk0 = umin32(k0, key);
                u32 nk1 = med3u(key, k0, k1);
                u32 nk2 = med3u(key, k1, k2);
                u32 nk3 = med3u(key, k2, k3);
                k0 = nk0; k1 = nk1; k2 = nk2; k3 = nk3;
            }
        }
        size_t o = ((size_t)b * NA + i) * 4;
        u32 ks[4] = {k0, k1, k2, k3};
        #pragma unroll
        for (int t = 0; t < 4; ++t) {
            idx_out[o + t] = (int)(ks[t] & 2047u);
            float d = sqrtf((float)(ks[t] >> 11)) * (1.0f / 128.0f);
            w_out[o + t] = 0.5f - fminf(d, 0.5f);
        }
    }
}

// ---------------------------------------------------------------------------
// C = A(f32) @ BT^T(bf16). BM=128, BN=256, BK=32, 4 waves (64m x 128n).
// A staged f32 via GLDS16 (src XOR-swizzled), cvt_pk->bf16 at fragment read.
// T4 counted-vmcnt pipeline: STAGE(t+1); vmcnt(8); barrier; compute; barrier.
// FUSED (P path): XCD m-swizzle, fused bias+relu+Q[idx]-gather epilogue with
// depth-2 gather pipeline (idx loads hoisted before the K-loop).
// ---------------------------------------------------------------------------
template<bool FUSED>
__global__ __launch_bounds__(256, 1) void gemm_kernel(
    const float* __restrict__ A, const u16* __restrict__ BT,
    u16* __restrict__ C, const int* __restrict__ idxb,
    const float* __restrict__ wb, const float* __restrict__ bias,
    const u16* __restrict__ Qb, float* __restrict__ out) {

    __shared__ __align__(16) char smem[FUSED ? 66560 : 65536];

    const int tid  = threadIdx.x;
    const int lane = tid & 63;
    const int wave = tid >> 6;
    const int mb   = blockIdx.x;
    const int m0   = FUSED ? ((((mb & 7) << 5) | (mb >> 3)) << 7) : (mb << 7);
    const int n0   = blockIdx.y << 8;
    const int l15  = lane & 15;
    const int fq   = lane >> 4;              // 0..3
    const int wr   = (wave >> 1) << 6;
    const int wc   = (wave & 1) << 7;

    // ---- staging descriptors: LDS dest linear, SOURCE pre-swizzled --------
    int aflat[4]; const float* asp[4];
    #pragma unroll
    for (int i = 0; i < 4; ++i) {
        int flat = i * 256 + tid;            // A: 128 rows x 8 f32 16B-quads
        int row = flat >> 3, pq = flat & 7;
        aflat[i] = flat;
        asp[i] = A + (size_t)(m0 + row) * DD + ((pq ^ (row & 7)) << 2);
    }
    int bflat[4]; const u16* bsp[4];
    #pragma unroll
    for (int i = 0; i < 4; ++i) {
        int flat = i * 256 + tid;            // B: 256 rows x 4 bf16 16B-quads
        int row = flat >> 2, pq = flat & 3;
        bflat[i] = flat;
        bsp[i] = BT + (size_t)(n0 + row) * DD + ((pq ^ ((row >> 1) & 3)) << 3);
    }

    // ---- fragment LDS byte offsets (same involution on read) --------------
    int aoff[4][2], boff[8];
    #pragma unroll
    for (int mf = 0; mf < 4; ++mf) {
        int R = wr + mf * 16 + l15;
        aoff[mf][0] = R * 128 + (((2 * fq) ^ (R & 7)) << 4);
        aoff[mf][1] = R * 128 + (((2 * fq + 1) ^ (R & 7)) << 4);
    }
    #pragma unroll
    for (int nf = 0; nf < 8; ++nf) {
        int R = wc + nf * 16 + l15;
        boff[nf] = 16384 + R * 64 + ((fq ^ ((R >> 1) & 3)) << 4);
    }

    // FUSED: hoist idx loads (ready at block start; frees tail latency)
    const int g16 = tid >> 4, l16 = tid & 15;
    const int r0g = g16 * 8;
    int4 iv[8];
    if (FUSED) {
        #pragma unroll
        for (int k = 0; k < 8; ++k)
            iv[k] = *(const int4*)(idxb + (size_t)(m0 + r0g + k) * 4);
    }

    f32x4 acc[4][8];
    #pragma unroll
    for (int mf = 0; mf < 4; ++mf)
        #pragma unroll
        for (int nf = 0; nf < 8; ++nf)
            acc[mf][nf] = (f32x4){0.f, 0.f, 0.f, 0.f};

#define STAGE(kk, bufb)                                                      \
    { _Pragma("unroll") for (int i = 0; i < 4; ++i)                          \
          GLDS16(asp[i] + (kk), smem + (bufb) + aflat[i] * 16);              \
      _Pragma("unroll") for (int i = 0; i < 4; ++i)                          \
          GLDS16(bsp[i] + (kk), smem + (bufb) + 16384 + bflat[i] * 16); }

    STAGE(0, 0);

    #pragma unroll 1
    for (int t = 0; t < 16; ++t) {
        const int cur = (t & 1) * 32768;
        if (t < 15) {
            STAGE((t + 1) * 32, 32768 - cur);
            asm volatile("s_waitcnt vmcnt(8)" ::: "memory");   // stage t done
        } else {
            asm volatile("s_waitcnt vmcnt(0)" ::: "memory");
        }
        __builtin_amdgcn_s_barrier();        // all waves' stage t visible

        bf16x8 af[4], bfr[8];
        #pragma unroll
        for (int mf = 0; mf < 4; ++mf) {
            f32x4 lo = *(const f32x4*)(smem + cur + aoff[mf][0]);
            f32x4 hi = *(const f32x4*)(smem + cur + aoff[mf][1]);
            af[mf] = cvt8(lo, hi);
        }
        #pragma unroll
        for (int nf = 0; nf < 8; ++nf)
            bfr[nf] = *(const bf16x8*)(smem + cur + boff[nf]);
        #pragma unroll
        for (int mf = 0; mf < 4; ++mf)
            #pragma unroll
            for (int nf = 0; nf < 8; ++nf)
                acc[mf][nf] = __builtin_amdgcn_mfma_f32_16x16x32_bf16(
                    af[mf], bfr[nf], acc[mf][nf], 0, 0, 0);

        __builtin_amdgcn_s_barrier();        // buf may be overwritten next t
    }

    const int r4 = (lane >> 4) * 4;

    if (!FUSED) {
        #pragma unroll
        for (int mf = 0; mf < 4; ++mf)
            #pragma unroll
            for (int nf = 0; nf < 8; ++nf)
                #pragma unroll
                for (int j = 0; j < 4; ++j) {
                    int row = m0 + wr + mf * 16 + r4 + j;
                    int col = n0 + wc + nf * 16 + l15;
                    C[(size_t)row * DD + col] = f2b_hw(acc[mf][nf][j]);
                }
        return;
    }

    // ---- fused epilogue: P' = acc + bias -> Ps (bf16), gather Q[idx] ------
    const u16* qs = Qb + ((size_t)(m0 >> 11) << 20);   // batch * 2048 * 512

    float bi[8];
    #pragma unroll
    for (int nf = 0; nf < 8; ++nf)
        bi[nf] = bias[n0 + wc + nf * 16 + l15];

    u16* Ps = (u16*)smem;                    // [128][260] bf16, 66560 B
    #pragma unroll
    for (int mf = 0; mf < 4; ++mf)
        #pragma unroll
        for (int nf = 0; nf < 8; ++nf)
            #pragma unroll
            for (int j = 0; j < 4; ++j)
                Ps[(wr + mf * 16 + r4 + j) * 260 + wc + nf * 16 + l15] =
                    f2b_hw(acc[mf][nf][j] + bi[nf]);

    // depth-2 gather pipeline: two static register banks (rule #20)
    bf16x8 qA0[8], qA1[8];

#define QLOAD(BANK, k)                                                       \
    { const size_t rx = (size_t)iv[k].x * DD, ry = (size_t)iv[k].y * DD,     \
                   rz = (size_t)iv[k].z * DD, rw = (size_t)iv[k].w * DD;     \
      _Pragma("unroll") for (int cc = 0; cc < 2; ++cc) {                     \
          const int col = n0 + cc * 128 + l16 * 8;                           \
          BANK[cc*4+0] = *(const bf16x8*)(qs + rx + col);                    \
          BANK[cc*4+1] = *(const bf16x8*)(qs + ry + col);                    \
          BANK[cc*4+2] = *(const bf16x8*)(qs + rz + col);                    \
          BANK[cc*4+3] = *(const bf16x8*)(qs + rw + col);                    \
      } }

#define QCONSUME(BANK, k)                                                    \
    { f32x4 wv = *(const f32x4*)(wb + (size_t)(m0 + r0g + (k)) * 4);         \
      _Pragma("unroll") for (int cc = 0; cc < 2; ++cc) {                     \
          const int col = cc * 128 + l16 * 8;                                \
          bf16x8 p8 = *(const bf16x8*)(Ps + (r0g + (k)) * 260 + col);        \
          float o[8];                                                        \
          _Pragma("unroll") for (int j = 0; j < 8; ++j) {                    \
              float p = b2f((u16)p8[j]);                                     \
              float s;                                                       \
              s  = fmaxf(p + b2f((u16)BANK[cc*4+0][j]), 0.f) * wv[0];        \
              s += fmaxf(p + b2f((u16)BANK[cc*4+1][j]), 0.f) * wv[1];        \
              s += fmaxf(p + b2f((u16)BANK[cc*4+2][j]), 0.f) * wv[2];        \
              s += fmaxf(p + b2f((u16)BANK[cc*4+3][j]), 0.f) * wv[3];        \
              o[j] = s;                                                      \
          }                                                                  \
          float* op = out + (size_t)(m0 + r0g + (k)) * 1024 + 512 + n0 + col;\
          *(f32x4*)op       = (f32x4){o[0], o[1], o[2], o[3]};               \
          *(f32x4*)(op + 4) = (f32x4){o[4], o[5], o[6], o[7]};               \
      } }

    // issue first two gather batches before the barrier (in flight across it)
    QLOAD(qA0, 0);
    QLOAD(qA1, 1);
    __syncthreads();

    QCONSUME(qA0, 0); QLOAD(qA0, 2);
    QCONSUME(qA1, 1); QLOAD(qA1, 3);
    QCONSUME(qA0, 2); QLOAD(qA0, 4);
    QCONSUME(qA1, 3); QLOAD(qA1, 5);
    QCONSUME(qA0, 4); QLOAD(qA0, 6);
    QCONSUME(qA1, 5); QLOAD(qA1, 7);
    QCONSUME(qA0, 6);
    QCONSUME(qA1, 7);
}

extern "C" void kernel_launch(void* const* d_in, const int* in_sizes, int n_in,
                              void* d_out, int out_size, void* d_ws, size_t ws_size,
                              hipStream_t stream) {
    const float* fa   = (const float*)d_in[0];
    const float* fb   = (const float*)d_in[1];
    const float* W    = (const float*)d_in[2];
    const float* bias = (const float*)d_in[3];
    const int*   ca   = (const int*)d_in[4];
    const int*   cb   = (const int*)d_in[5];
    float* out = (float*)d_out;

    char* ws = (char*)d_ws;
    u16*   Qb   = (u16*)(ws);                       // 32 MB bf16 Q
    u16*   W2T  = (u16*)(ws + 33554432);            // 512 KB
    u16*   WdT  = (u16*)(ws + 34078720);            // 512 KB
    int*   idxb = (int*)(ws + 34603008);            // 512 KB
    float* wb   = (float*)(ws + 35127296);          // 512 KB

    topk_prep<<<320, 512, 0, stream>>>(ca, cb, idxb, wb, fa, out,
                                       W, W2T, WdT);

    dim3 gg(256, 2);
    gemm_kernel<false><<<gg, 256, 0, stream>>>(fb, WdT, Qb, nullptr, nullptr,
                                               nullptr, nullptr, nullptr);
    gemm_kernel<true><<<gg, 256, 0, stream>>>(fa, W2T, nullptr, idxb, wb,
                                              bias, Qb, out);
}